// Round 1
// 79.147 us; speedup vs baseline: 1.0205x; 1.0205x over previous
//
#include <hip/hip_runtime.h>
#include <math.h>

// Problem constants (fixed by the reference's setup_inputs)
#define CLS 2
#define BATCH 8
#define HH 512
#define WW 512
#define INV_SCALE 0.125f
#define LOGEPS -16.118095651f   // log(1e-7)

#define MAXT 256     // LDS capacity for per-batch targets (nT<=160 total)
#define NBLK 2048    // grid: 8*512*512 px / 1024 px-per-block

// ws layout (NO zero-init required anywhere — every slot written unconditionally):
//   double gsumd[4][NBLK]  @ 0      (65536 B)  obj_c0, obj_c1, noobj_c0, noobj_c1
//   int    gcnti[2][NBLK]  @ 65536  (16384 B)  packed obj counts, packed noobj counts

// One fused kernel: per-block target staging (replaces heatmap_prep) +
// per-wave strip processing + per-block partial write (replaces atomics).
// 256 threads = 4 waves; each wave owns one 256-px row strip.
__global__ __launch_bounds__(256) void heatmap_main(
    const float* __restrict__ predict, const float* __restrict__ targets,
    int nT, float* __restrict__ out,
    double* __restrict__ gsumd, int* __restrict__ gcnti)
{
    __shared__ float s_cs[MAXT], s_sn[MAXT], s_x3[MAXT], s_x4[MAXT],
                     s_y3[MAXT], s_y4[MAXT];
    __shared__ int s_cid[MAXT];
    __shared__ int s_nb;
    __shared__ double s_bs[4][4];
    __shared__ int s_bc[4][2];

    const int tid = threadIdx.x;
    const int blockPix = blockIdx.x << 10;      // 1024 px per block
    const int b = blockPix >> 18;               // / (H*W); uniform per block

    // --- stage this batch's targets into LDS (compacted) ---
    if (tid == 0) s_nb = 0;
    __syncthreads();
    for (int t0 = tid; t0 < nT; t0 += 256) {
        const float* tp = targets + t0 * 7;
        if ((int)tp[0] == b) {
            const float cs = cosf(tp[6]), sn = sinf(tp[6]);
            const float cx = tp[2] * INV_SCALE, cy = tp[3] * INV_SCALE;
            const float w_ = tp[4] * INV_SCALE, h_ = tp[5] * INV_SCALE;
            const float x =  cx * cs + cy * sn;
            const float y = -cx * sn + cy * cs;
            const int slot = atomicAdd(&s_nb, 1);
            s_cs[slot] = cs; s_sn[slot] = sn;
            s_x3[slot] = x - 0.5f * h_; s_x4[slot] = x + 0.5f * h_;
            s_y3[slot] = y - 0.5f * w_; s_y4[slot] = y + 0.5f * w_;
            s_cid[slot] = (int)tp[1];
        }
    }
    __syncthreads();
    const int nb = s_nb;

    const int wid = tid >> 6;
    const int l   = tid & 63;
    const int spix = blockPix + (wid << 8);     // strip base pixel
    const int i  = (spix >> 9) & (HH - 1);      // row
    const int j0 = spix & (WW - 1);             // 0 or 256
    const float gy = (float)i + 0.5f;
    const int j = j0 + 4 * l;
    const float gxb = (float)j + 0.5f;

    int objm[4] = {0, 0, 0, 0}, outm[4] = {0, 0, 0, 0};

    for (int base = 0; base < nb; base += 64) {
        const int t = base + l;
        bool acc = false;
        if (t < nb) {
            const float cs = s_cs[t], sn = s_sn[t];
            // strip: gx in [j0+0.5, j0+255.5], gy fixed -> exact vx/vy intervals
            const float gxl = (float)j0 + 0.5f, gxh = (float)j0 + 255.5f;
            const float a1 = cs * gxl + sn * gy, a2 = cs * gxh + sn * gy;
            const float b1 = -sn * gxl + cs * gy, b2 = -sn * gxh + cs * gy;
            const float vxlo = fminf(a1, a2), vxhi = fmaxf(a1, a2);
            const float vylo = fminf(b1, b2), vyhi = fmaxf(b1, b2);
            const float M = 0.51f;  // outer margin 0.5 + fp slack
            acc = (vxhi >= s_x3[t] - M) & (vxlo <= s_x4[t] + M) &
                  (vyhi >= s_y3[t] - M) & (vylo <= s_y4[t] + M);
        }
        unsigned long long bal = __ballot(acc);   // wave-uniform hit mask
        while (bal) {
            const int n = base + __builtin_ctzll(bal);  // uniform target index
            bal &= bal - 1;
            // uniform-address LDS reads = hardware broadcast (replaces shfl)
            const float ccs = s_cs[n], csn = s_sn[n];
            const float cx3 = s_x3[n], cx4 = s_x4[n];
            const float cy3 = s_y3[n], cy4 = s_y4[n];
            const int cbit = 1 << s_cid[n];
            float vx =  ccs * gxb + csn * gy;
            float vy = -csn * gxb + ccs * gy;
            #pragma unroll
            for (int k = 0; k < 4; ++k) {
                const bool in_  = (cx3 <= vx) & (vx <= cx4) &
                                  (cy3 <= vy) & (vy <= cy4);
                const bool out_ = (cx3 - 0.5f <= vx) & (vx <= cx4 + 0.5f) &
                                  (cy3 - 0.5f <= vy) & (vy <= cy4 + 0.5f);
                if (in_)  objm[k] |= cbit;
                if (out_) outm[k] |= cbit;
                vx += ccs; vy -= csn;
            }
        }
    }

    // --- vectorized loads; sigmoid/log algebra (5 transcendentals/px) ---
    const int pbase = (b * CLS * HH + i) * WW + j;   // 16B-aligned (j = 4l)
    const float4 P0 = *(const float4*)(predict + pbase);
    const float4 P1 = *(const float4*)(predict + pbase + HH * WW);

    float so0 = 0.f, so1 = 0.f, sq0 = 0.f, sq1 = 0.f;
    int c_obj0 = 0, c_obj1 = 0, c_no0 = 0, c_no1 = 0;
    float hm[4];
    #pragma unroll
    for (int k = 0; k < 4; ++k) {
        const float p0 = (&P0.x)[k], p1 = (&P1.x)[k];
        const float t0 = __expf(p0), t1 = __expf(p1);
        const float l0n = -__logf(1.0f + t0);       // log(1-conf0)
        const float l1n = -__logf(1.0f + t1);
        const float lc0 = fmaxf(p0 + l0n, LOGEPS);  // log(conf0), EPS-clipped
        const float lc1 = fmaxf(p1 + l1n, LOGEPS);
        const float l0c = fmaxf(l0n, LOGEPS);
        const float l1c = fmaxf(l1n, LOGEPS);
        const float tm = fmaxf(t0, t1);
        hm[k] = tm * __builtin_amdgcn_rcpf(1.0f + tm);  // sigmoid(max(p0,p1))
        const int om = objm[k], um = outm[k];
        if (om & 1) { so0 += lc0; ++c_obj0; }
        if (om & 2) { so1 += lc1; ++c_obj1; }
        if (!(um & 1)) { sq0 += l0c; ++c_no0; }
        if (!(um & 2)) { sq1 += l1c; ++c_no1; }
    }

    float* ho = out + 1 + (b * HH + i) * WW + j;  // +1: misaligned -> 4 dwords
    ho[0] = hm[0]; ho[1] = hm[1]; ho[2] = hm[2]; ho[3] = hm[3];

    // --- wave reduction; obj trees skipped wave-uniformly when empty ---
    const unsigned long long anyobj =
        __ballot((objm[0] | objm[1] | objm[2] | objm[3]) != 0);
    int pc = (c_no0 & 0xffff) | (c_no1 << 16);
    #pragma unroll
    for (int off = 32; off >= 1; off >>= 1) {
        sq0 += __shfl_down(sq0, off);
        sq1 += __shfl_down(sq1, off);
        pc  += __shfl_down(pc, off);
    }
    int po = 0;
    if (anyobj) {
        po = (c_obj0 & 0xffff) | (c_obj1 << 16);
        #pragma unroll
        for (int off = 32; off >= 1; off >>= 1) {
            so0 += __shfl_down(so0, off);
            so1 += __shfl_down(so1, off);
            po  += __shfl_down(po, off);
        }
    }
    if (l == 0) {
        s_bs[wid][0] = (double)so0; s_bs[wid][1] = (double)so1;
        s_bs[wid][2] = (double)sq0; s_bs[wid][3] = (double)sq1;
        s_bc[wid][0] = po;          s_bc[wid][1] = pc;
    }
    __syncthreads();
    // --- per-block partial: plain writes, no atomics, no pre-zeroed ws ---
    if (tid == 0) {
        double o0 = 0, o1 = 0, q0 = 0, q1 = 0;
        int P = 0, Q = 0;  // packed 16-bit fields; <=1024 each, no carry
        #pragma unroll
        for (int w = 0; w < 4; ++w) {
            o0 += s_bs[w][0]; o1 += s_bs[w][1];
            q0 += s_bs[w][2]; q1 += s_bs[w][3];
            P  += s_bc[w][0]; Q  += s_bc[w][1];
        }
        const int blk = blockIdx.x;
        gsumd[0 * NBLK + blk] = o0; gsumd[1 * NBLK + blk] = o1;
        gsumd[2 * NBLK + blk] = q0; gsumd[3 * NBLK + blk] = q1;
        gcnti[0 * NBLK + blk] = P;  gcnti[1 * NBLK + blk] = Q;
    }
}

__global__ __launch_bounds__(512) void heatmap_finalize(
    const double* __restrict__ gsumd, const int* __restrict__ gcnti,
    float* __restrict__ out)
{
    const int t = threadIdx.x;
    double f[4] = {0, 0, 0, 0};
    int co0 = 0, co1 = 0, cn0 = 0, cn1 = 0;
    for (int blk = t; blk < NBLK; blk += 512) {     // coalesced SoA reads
        #pragma unroll
        for (int q = 0; q < 4; ++q) f[q] += gsumd[q * NBLK + blk];
        const int p = gcnti[0 * NBLK + blk];
        const int q2 = gcnti[1 * NBLK + blk];
        co0 += p & 0xffff;  co1 += p >> 16;         // unpack BEFORE summing
        cn0 += q2 & 0xffff; cn1 += q2 >> 16;        // (totals exceed 16 bits)
    }
    #pragma unroll
    for (int off = 32; off >= 1; off >>= 1) {
        #pragma unroll
        for (int q = 0; q < 4; ++q) f[q] += __shfl_down(f[q], off);
        co0 += __shfl_down(co0, off); co1 += __shfl_down(co1, off);
        cn0 += __shfl_down(cn0, off); cn1 += __shfl_down(cn1, off);
    }

    __shared__ double sf[8][4];
    __shared__ int    sc[8][4];
    const int wv = t >> 6, ln = t & 63;
    if (ln == 0) {
        #pragma unroll
        for (int q = 0; q < 4; ++q) sf[wv][q] = f[q];
        sc[wv][0] = co0; sc[wv][1] = co1; sc[wv][2] = cn0; sc[wv][3] = cn1;
    }
    __syncthreads();
    if (t == 0) {
        double F[4] = {0, 0, 0, 0}; int C[4] = {0, 0, 0, 0};
        for (int w = 0; w < 8; ++w)
            #pragma unroll
            for (int q = 0; q < 4; ++q) { F[q] += sf[w][q]; C[q] += sc[w][q]; }
        float loss = 0.0f;
        // C[0]=n_obj cls0, C[1]=n_obj cls1, C[2]=n_noobj cls0, C[3]=n_noobj cls1
        if (C[0] > 0)
            loss += -(float)F[0] / (float)C[0]
                    - (float)F[2] / (float)(C[2] > 0 ? C[2] : 1);
        if (C[1] > 0)
            loss += -(float)F[1] / (float)C[1]
                    - (float)F[3] / (float)(C[3] > 0 ? C[3] : 1);
        out[0] = loss;  // NO_OBJ_SCALE = 1.0
    }
}

extern "C" void kernel_launch(void* const* d_in, const int* in_sizes, int n_in,
                              void* d_out, int out_size, void* d_ws, size_t ws_size,
                              hipStream_t stream) {
    const float* predict = (const float*)d_in[0];
    const float* targets = (const float*)d_in[1];
    const int nT = in_sizes[1] / 7;
    float* out = (float*)d_out;
    char* ws = (char*)d_ws;
    double* gsumd = (double*)ws;            // 4*2048*8 = 65536 B
    int* gcnti = (int*)(ws + 65536);        // 2*2048*4 = 16384 B

    heatmap_main<<<NBLK, 256, 0, stream>>>(predict, targets, nT, out,
                                           gsumd, gcnti);
    heatmap_finalize<<<1, 512, 0, stream>>>(gsumd, gcnti, out);
}